// Round 1
// baseline (328.929 us; speedup 1.0000x reference)
//
#include <hip/hip_runtime.h>

#define THRESH 0.05f

typedef __attribute__((ext_vector_type(4))) int int32x4;

// ---------------------------------------------------------------------------
// Kernel 1: quantize weight [1024,1024] fp32 -> int8 {-1,0,+1} into d_ws.
// One float4 per thread, packed into one int store. 4 MB read / 1 MB write.
// ---------------------------------------------------------------------------
__global__ __launch_bounds__(256) void quant_w_kernel(const float* __restrict__ w,
                                                      int* __restrict__ wq) {
    int idx = blockIdx.x * 256 + threadIdx.x;   // float4 index
    const float4* w4 = (const float4*)w;
    float4 f = w4[idx];
    int q0 = (f.x >= THRESH) - (f.x <= -THRESH);
    int q1 = (f.y >= THRESH) - (f.y <= -THRESH);
    int q2 = (f.z >= THRESH) - (f.z <= -THRESH);
    int q3 = (f.w >= THRESH) - (f.w <= -THRESH);
    wq[idx] = (q0 & 0xff) | ((q1 & 0xff) << 8) | ((q2 & 0xff) << 16) | ((q3 & 0xff) << 24);
}

// ---------------------------------------------------------------------------
// Kernel 2: slab-resident ternary GEMM.
// Block = 64 rows x 1024 cols. Phase 1: quantize the 64x1024 fp32 x-slab into
// 64 KB of LDS int8 (XOR-swizzled: chunk' = chunk ^ (row&7) for conflict-free
// ds_read_b128). Phase 2 (no further barriers): 4 waves, each covers 256 cols
// as 4 col-tiles of 64; per tile, 16 K-steps of 4x4 mfma_i32_16x16x64_i8.
// A-frags from LDS, B-frags direct from global wq (L2-resident, 1 MB).
// ---------------------------------------------------------------------------
__global__ __launch_bounds__(256, 2) void tern_gemm_kernel(const float* __restrict__ x,
                                                           const signed char* __restrict__ wq,
                                                           float* __restrict__ out) {
    __shared__ __attribute__((aligned(16))) signed char a_lds[64 * 1024];
    const int tid = threadIdx.x;
    const long rowbase = (long)blockIdx.x * 64;

    // ---- Phase 1: stage + quantize x slab (64 rows x 1024 K) ----
    // 4096 16-byte chunks, 16 per thread; consecutive threads take
    // consecutive chunks within a row -> fully coalesced 64B/lane-group reads.
    #pragma unroll
    for (int i = 0; i < 16; ++i) {
        int c   = tid + i * 256;   // chunk id 0..4095
        int row = c >> 6;          // 64 chunks per row
        int cir = c & 63;          // chunk-in-row
        const float4* src = (const float4*)(x + (rowbase + row) * 1024 + cir * 16);
        signed char q[16];
        #pragma unroll
        for (int j = 0; j < 4; ++j) {
            float4 f = src[j];
            q[j * 4 + 0] = (signed char)((f.x >= THRESH) - (f.x <= -THRESH));
            q[j * 4 + 1] = (signed char)((f.y >= THRESH) - (f.y <= -THRESH));
            q[j * 4 + 2] = (signed char)((f.z >= THRESH) - (f.z <= -THRESH));
            q[j * 4 + 3] = (signed char)((f.w >= THRESH) - (f.w <= -THRESH));
        }
        int swz = (cir ^ (row & 7)) * 16;  // XOR swizzle: uniform bank spread
        *(int32x4*)(a_lds + row * 1024 + swz) = *(const int32x4*)q;
    }
    __syncthreads();

    // ---- Phase 2: compute ----
    const int wave = tid >> 6;
    const int lane = tid & 63;
    const int l15  = lane & 15;
    const int lq   = lane >> 4;   // lane quarter: selects contiguous K/4 chunk

    for (int ct = 0; ct < 4; ++ct) {
        const int cb = wave * 256 + ct * 64;   // this wave's 64-col tile base
        int32x4 acc[4][4];
        #pragma unroll
        for (int ri = 0; ri < 4; ++ri)
            #pragma unroll
            for (int ci = 0; ci < 4; ++ci)
                acc[ri][ci] = (int32x4){0, 0, 0, 0};

        for (int k = 0; k < 16; ++k) {          // K-steps of 64
            const int kchunk = k * 4 + lq;      // 16B chunk index along K

            int32x4 afrag[4];
            #pragma unroll
            for (int ri = 0; ri < 4; ++ri) {
                int m = ri * 16 + l15;
                afrag[ri] = *(const int32x4*)(a_lds + m * 1024 + ((kchunk ^ (m & 7)) * 16));
            }

            int32x4 bfrag[4];
            #pragma unroll
            for (int ci = 0; ci < 4; ++ci) {
                long col = cb + ci * 16 + l15;
                bfrag[ci] = *(const int32x4*)(wq + col * 1024 + kchunk * 16);
            }

            #pragma unroll
            for (int ri = 0; ri < 4; ++ri)
                #pragma unroll
                for (int ci = 0; ci < 4; ++ci)
                    acc[ri][ci] = __builtin_amdgcn_mfma_i32_16x16x64_i8(
                        afrag[ri], bfrag[ci], acc[ri][ci], 0, 0, 0);
        }

        // ---- epilogue: C/D layout col=lane&15, row=(lane>>4)*4+reg ----
        #pragma unroll
        for (int ri = 0; ri < 4; ++ri) {
            #pragma unroll
            for (int ci = 0; ci < 4; ++ci) {
                const long row = rowbase + ri * 16 + lq * 4;
                const int  col = cb + ci * 16 + l15;
                float* o = out + row * 1024 + col;
                o[0 * 1024] = (float)acc[ri][ci][0];
                o[1 * 1024] = (float)acc[ri][ci][1];
                o[2 * 1024] = (float)acc[ri][ci][2];
                o[3 * 1024] = (float)acc[ri][ci][3];
            }
        }
    }
}

extern "C" void kernel_launch(void* const* d_in, const int* in_sizes, int n_in,
                              void* d_out, int out_size, void* d_ws, size_t ws_size,
                              hipStream_t stream) {
    const float* x = (const float*)d_in[0];      // [32768, 1024] fp32
    const float* w = (const float*)d_in[1];      // [1024, 1024] fp32
    float* out = (float*)d_out;                  // [32768, 1024] fp32
    signed char* wq = (signed char*)d_ws;        // 1 MB int8 scratch

    // quantize weight: 1024*1024/4 float4s / 256 threads = 1024 blocks
    quant_w_kernel<<<dim3(1024), dim3(256), 0, stream>>>(w, (int*)wq);
    // main GEMM: 32768 rows / 64 = 512 blocks (2 per CU)
    tern_gemm_kernel<<<dim3(512), dim3(256), 0, stream>>>(x, wq, out);
}